// Round 2
// baseline (749.340 us; speedup 1.0000x reference)
//
#include <hip/hip_runtime.h>

#define B_ 64
#define A_ 128
#define M_ 8
#define D_ 384
#define O0_ 256
#define O2_ 192
#define O4_ 160

typedef float f32x4 __attribute__((ext_vector_type(4)));
typedef _Float16 f16x8 __attribute__((ext_vector_type(8)));
typedef _Float16 f16x4 __attribute__((ext_vector_type(4)));

__device__ __forceinline__ float celu_f(float x) {
    // F.celu(x, 0.1) = x>0 ? x : 0.1*(exp(x/0.1)-1)
    return x > 0.f ? x : 0.1f * (__expf(x * 10.f) - 1.f);
}

__device__ __forceinline__ f32x4 zero4() {
    f32x4 v; v[0] = 0.f; v[1] = 0.f; v[2] = 0.f; v[3] = 0.f; return v;
}

// Generic MFMA layer: X_out[b][o] = celu(W[o][:] . X_in[b][:] + bias[o])
// X_in: LDS fp16 [64][K], 16B-chunk swizzled (chunk ^ (b&7)).
// X_out: LDS fp16 [64][OPITCH]; swizzled if SWZ_OUT else plain.
// 8 waves per block; wave w owns output tiles w, w+8, ...
template<int K, int O, int OPITCH, bool SWZ_OUT>
__device__ __forceinline__ void layer_mfma(const float* __restrict__ W,
                                           const float* __restrict__ bias,
                                           const _Float16* Xin, _Float16* Xout,
                                           int wave, int col, int quad)
{
    constexpr int KSTEPS = K / 32;
    constexpr int OTILES = O / 16;
    for (int ot = wave; ot < OTILES; ot += 8) {
        const float* wrow = W + (size_t)(ot * 16 + col) * K + quad * 8;
        f32x4 acc[4];
        #pragma unroll
        for (int nt = 0; nt < 4; ++nt) acc[nt] = zero4();
        #pragma unroll
        for (int ks = 0; ks < KSTEPS; ++ks) {
            f32x4 wlo = *(const f32x4*)(wrow + ks * 32);
            f32x4 whi = *(const f32x4*)(wrow + ks * 32 + 4);
            f16x8 afr;
            afr[0] = (_Float16)wlo[0]; afr[1] = (_Float16)wlo[1];
            afr[2] = (_Float16)wlo[2]; afr[3] = (_Float16)wlo[3];
            afr[4] = (_Float16)whi[0]; afr[5] = (_Float16)whi[1];
            afr[6] = (_Float16)whi[2]; afr[7] = (_Float16)whi[3];
            #pragma unroll
            for (int nt = 0; nt < 4; ++nt) {
                const int b = nt * 16 + col;
                const int c = ks * 4 + quad;
                const f16x8 bfr = *(const f16x8*)(Xin + b * K + ((c ^ (b & 7)) * 8));
                acc[nt] = __builtin_amdgcn_mfma_f32_16x16x32_f16(afr, bfr, acc[nt], 0, 0, 0);
            }
        }
        // epilogue: bias + celu, transposed store to Xout[b][o]
        const f32x4 bias4 = *(const f32x4*)(bias + ot * 16 + quad * 4);
        const int o0 = ot * 16 + quad * 4;
        #pragma unroll
        for (int nt = 0; nt < 4; ++nt) {
            const int b = nt * 16 + col;
            f16x4 h;
            #pragma unroll
            for (int r = 0; r < 4; ++r) h[r] = (_Float16)celu_f(acc[nt][r] + bias4[r]);
            if (SWZ_OUT) {
                const int c = o0 >> 3;
                *(f16x4*)(Xout + b * OPITCH + ((c ^ (b & 7)) * 8) + (o0 & 7)) = h;
            } else {
                *(f16x4*)(Xout + b * OPITCH + o0) = h;
            }
        }
    }
}

// 512 threads (8 waves) per block; 2 blocks/CU under the 56 KiB LDS floor
// gives 16 waves/CU (4/SIMD) vs 8 before -> 2x memory-level parallelism.
// __launch_bounds__(512,4): 4 waves/EU min => VGPR cap 128 (per-wave state
// halved vs the 256-thread version, so this should not spill).
__global__ __launch_bounds__(512, 4) void nn_kernel(
    const float* __restrict__ aev,
    const float* __restrict__ w0, const float* __restrict__ b0,
    const float* __restrict__ w2, const float* __restrict__ b2,
    const float* __restrict__ w4, const float* __restrict__ b4,
    const float* __restrict__ w6, const float* __restrict__ b6,
    float* __restrict__ out)
{
    // LDS plan (bytes):
    //   bufStage: [0, 24576)        64 x 192 fp16, swizzled (aev k-chunk)
    //   X0      : [24576, 57344)    64 x 256 fp16, swizzled
    //   X2      : [0, 24576)        64 x 192 fp16, swizzled   (bufStage dead)
    //   X4      : [24576, 45568)    64 x 164 fp16, plain      (X0 dead)
    //   part    : [45568, 47616)    512 fp32
    __shared__ __align__(16) unsigned char smem_raw[57344];
    _Float16* const lds = (_Float16*)smem_raw;

    const int tid  = threadIdx.x;
    const int wave = tid >> 6;     // 0..7
    const int lane = tid & 63;
    const int col  = lane & 15;
    const int quad = lane >> 4;

    // XCD-locality: the 8 model-blocks of one atom share the atom's aev rows.
    // With a = bid>>3 they round-robin onto 8 different XCD L2s (zero reuse);
    // with a = bid&127 they all land on the same XCD (bid mod 8 fixed per atom).
    const int a  = blockIdx.x & 127;
    const int m  = blockIdx.x >> 7;
    const int am = a * 8 + m;

    const float* w0p = w0 + (size_t)am * O0_ * D_;
    const float* b0p = b0 + am * O0_;
    const float* w2p = w2 + (size_t)am * O2_ * O0_;
    const float* b2p = b2 + am * O2_;
    const float* w4p = w4 + (size_t)am * O4_ * O2_;
    const float* b4p = b4 + am * O4_;
    const float* w6p = w6 + am * O4_;
    const float  b6v = b6[am];

    _Float16* bufStage = lds;                 // 64 x 192
    _Float16* X0 = lds + 12288;               // 64 x 256 (byte off 24576)
    _Float16* X2 = lds;                       // 64 x 192
    _Float16* X4 = lds + 12288;               // 64 x 164 plain
    float* part = (float*)(smem_raw + 45568);

    // ---------------- Layer 0: 384 -> 256, aev staged in two 192-K chunks ----
    f32x4 acc0[2][4];
    #pragma unroll
    for (int i = 0; i < 2; ++i)
        #pragma unroll
        for (int nt = 0; nt < 4; ++nt) acc0[i][nt] = zero4();

    #pragma unroll
    for (int kc = 0; kc < 2; ++kc) {
        if (kc) __syncthreads();  // all reads of previous chunk done
        // cooperative stage: 64 rows x 24 chunks of 8 fp32 -> fp16 swizzled
        #pragma unroll
        for (int it = 0; it < 3; ++it) {
            const int idx = tid + it * 512;
            const int b = idx / 24;
            const int c = idx % 24;
            const float* src = aev + ((size_t)b * A_ + a) * D_ + kc * 192 + c * 8;
            f32x4 lo = *(const f32x4*)src;
            f32x4 hi = *(const f32x4*)(src + 4);
            f16x8 h;
            h[0] = (_Float16)lo[0]; h[1] = (_Float16)lo[1];
            h[2] = (_Float16)lo[2]; h[3] = (_Float16)lo[3];
            h[4] = (_Float16)hi[0]; h[5] = (_Float16)hi[1];
            h[6] = (_Float16)hi[2]; h[7] = (_Float16)hi[3];
            *(f16x8*)(bufStage + b * 192 + ((c ^ (b & 7)) * 8)) = h;
        }
        __syncthreads();
        #pragma unroll
        for (int i = 0; i < 2; ++i) {
            const int ot = wave + i * 8;
            const float* wrow = w0p + (size_t)(ot * 16 + col) * D_ + kc * 192 + quad * 8;
            #pragma unroll
            for (int ks = 0; ks < 6; ++ks) {
                f32x4 wlo = *(const f32x4*)(wrow + ks * 32);
                f32x4 whi = *(const f32x4*)(wrow + ks * 32 + 4);
                f16x8 afr;
                afr[0] = (_Float16)wlo[0]; afr[1] = (_Float16)wlo[1];
                afr[2] = (_Float16)wlo[2]; afr[3] = (_Float16)wlo[3];
                afr[4] = (_Float16)whi[0]; afr[5] = (_Float16)whi[1];
                afr[6] = (_Float16)whi[2]; afr[7] = (_Float16)whi[3];
                #pragma unroll
                for (int nt = 0; nt < 4; ++nt) {
                    const int b = nt * 16 + col;
                    const int c = ks * 4 + quad;
                    const f16x8 bfr = *(const f16x8*)(bufStage + b * 192 + ((c ^ (b & 7)) * 8));
                    acc0[i][nt] = __builtin_amdgcn_mfma_f32_16x16x32_f16(afr, bfr, acc0[i][nt], 0, 0, 0);
                }
            }
        }
    }
    // L0 epilogue -> X0 (pitch 256, swizzled). X0 region untouched so far.
    #pragma unroll
    for (int i = 0; i < 2; ++i) {
        const int ot = wave + i * 8;
        const f32x4 bias4 = *(const f32x4*)(b0p + ot * 16 + quad * 4);
        const int o0 = ot * 16 + quad * 4;
        #pragma unroll
        for (int nt = 0; nt < 4; ++nt) {
            const int b = nt * 16 + col;
            f16x4 h;
            #pragma unroll
            for (int r = 0; r < 4; ++r) h[r] = (_Float16)celu_f(acc0[i][nt][r] + bias4[r]);
            const int c = o0 >> 3;
            *(f16x4*)(X0 + b * 256 + ((c ^ (b & 7)) * 8) + (o0 & 7)) = h;
        }
    }
    __syncthreads();

    // ---------------- Layer 2: 256 -> 192 ----------------
    layer_mfma<256, 192, 192, true>(w2p, b2p, X0, X2, wave, col, quad);
    __syncthreads();

    // ---------------- Layer 4: 192 -> 160 (plain X4, pitch 164) -------------
    layer_mfma<192, 160, 164, false>(w4p, b4p, X2, X4, wave, col, quad);
    __syncthreads();

    // ---------------- Layer 6: 160 -> 1, VALU dot ----------------
    {
        const int b  = tid & 63;
        const int pt = tid >> 6;              // 0..7, 20 elems each
        const _Float16* xrow = X4 + b * 164 + pt * 20;
        const float* wseg = w6p + pt * 20;
        float s = 0.f;
        #pragma unroll
        for (int j = 0; j < 5; ++j) {
            f32x4 wv = *(const f32x4*)(wseg + j * 4);
            f16x4 xv = *(const f16x4*)(xrow + j * 4);
            s += wv[0] * (float)xv[0] + wv[1] * (float)xv[1] +
                 wv[2] * (float)xv[2] + wv[3] * (float)xv[3];
        }
        part[tid] = s;
    }
    __syncthreads();
    if (tid < 64) {
        float x6 = b6v;
        #pragma unroll
        for (int p = 0; p < 8; ++p) x6 += part[tid + 64 * p];
        atomicAdd(out + B_ * A_ + tid, x6 * 0.125f);  // /M
    }
}

__global__ void init_out_kernel(const int* __restrict__ species, float* __restrict__ out) {
    const int i = blockIdx.x * 256 + threadIdx.x;
    if (i < B_ * A_) out[i] = (float)species[i];
    if (i < B_) out[B_ * A_ + i] = 0.f;
}

extern "C" void kernel_launch(void* const* d_in, const int* in_sizes, int n_in,
                              void* d_out, int out_size, void* d_ws, size_t ws_size,
                              hipStream_t stream) {
    const int*   species = (const int*)d_in[0];
    const float* aev = (const float*)d_in[1];
    const float* w0  = (const float*)d_in[2];
    const float* b0  = (const float*)d_in[3];
    const float* w2  = (const float*)d_in[4];
    const float* b2  = (const float*)d_in[5];
    const float* w4  = (const float*)d_in[6];
    const float* b4  = (const float*)d_in[7];
    const float* w6  = (const float*)d_in[8];
    const float* b6  = (const float*)d_in[9];
    float* out = (float*)d_out;

    hipLaunchKernelGGL(init_out_kernel, dim3(32), dim3(256), 0, stream, species, out);
    hipLaunchKernelGGL(nn_kernel, dim3(A_ * M_), dim3(512), 0, stream,
                       aev, w0, b0, w2, b2, w4, b4, w6, b6, out);
}

// Round 3
// 735.053 us; speedup vs baseline: 1.0194x; 1.0194x over previous
//
#include <hip/hip_runtime.h>

#define B_ 64
#define A_ 128
#define M_ 8
#define D_ 384
#define O0_ 256
#define O2_ 192
#define O4_ 160

typedef float f32x4 __attribute__((ext_vector_type(4)));
typedef _Float16 f16x8 __attribute__((ext_vector_type(8)));
typedef _Float16 f16x4 __attribute__((ext_vector_type(4)));

__device__ __forceinline__ float celu_f(float x) {
    // F.celu(x, 0.1) = x>0 ? x : 0.1*(exp(x/0.1)-1)
    return x > 0.f ? x : 0.1f * (__expf(x * 10.f) - 1.f);
}

__device__ __forceinline__ f32x4 zero4() {
    f32x4 v; v[0] = 0.f; v[1] = 0.f; v[2] = 0.f; v[3] = 0.f; return v;
}

// Async global->LDS, 16 B/lane. LDS dest is wave-uniform base + lane*16 (HW);
// global src is per-lane.
#define GLOAD_LDS16(gp, lp)                                                     \
    __builtin_amdgcn_global_load_lds(                                           \
        (const __attribute__((address_space(1))) void*)(gp),                    \
        (__attribute__((address_space(3))) void*)(lp), 16, 0, 0)

// Stage a 32-row x KH-f32 weight panel (rows row0..row0+32 of a [O][K] f32
// matrix, cols col0..col0+KH) into LDS, linear row-major [32][KH].
// Source applies the XOR-chunk swizzle so that a read of logical 16B-chunk q
// of row r must access LDS chunk q^(r&7)  (conflict-free ds_read_b128:
// any 8 consecutive lanes cover all 8 bank groups).
// Each wave issues CALLS fire-and-forget 1-KB contiguous global_load_lds.
template<int K, int KH>
__device__ __forceinline__ void stage_panel(const float* __restrict__ W,
                                            int row0, int col0,
                                            unsigned char* panelBase,
                                            int wave, int lane)
{
    constexpr int CPR   = KH / 4;                   // 16B chunks per row
    constexpr int CALLS = (32 * KH * 4) / (1024 * 8);
    #pragma unroll
    for (int j = 0; j < CALLS; ++j) {
        const int cb = (wave * CALLS + j);          // 1-KB block index
        const int C  = cb * 64 + lane;              // 16B chunk index in panel
        const int r  = C / CPR;
        const int q  = C % CPR;
        const int gq = q ^ (r & 7);
        const float* src = W + (size_t)(row0 + r) * K + col0 + gq * 4;
        GLOAD_LDS16(src, panelBase + cb * 1024);
    }
}

// Read one MFMA A-fragment (8 f16 covering k = ksl*32 + quad*8 .. +8) for
// panel row rr from a staged f32 panel (row-major [32][KH], XOR-swizzled).
template<int KH>
__device__ __forceinline__ f16x8 read_afrag(const unsigned char* panelBase,
                                            int rr, int ksl, int quad)
{
    const float* row = (const float*)(panelBase + rr * (KH * 4));
    const int q0 = quad * 2 + ksl * 8;
    const f32x4 lo = *(const f32x4*)(row + ((q0 ^ (rr & 7)) * 4));
    const f32x4 hi = *(const f32x4*)(row + (((q0 + 1) ^ (rr & 7)) * 4));
    f16x8 a;
    a[0] = (_Float16)lo[0]; a[1] = (_Float16)lo[1];
    a[2] = (_Float16)lo[2]; a[3] = (_Float16)lo[3];
    a[4] = (_Float16)hi[0]; a[5] = (_Float16)hi[1];
    a[6] = (_Float16)hi[2]; a[7] = (_Float16)hi[3];
    return a;
}

// LDS plan (bytes), total 81920 = exactly 160KiB/2 -> 2 blocks/CU:
//   AEVBUF : [0, 24576)        64 x 192 f16 swizzled (one K-half of aev)
//   PANEL0 : [24576, 49152)    32 x 192 f32 weight panel (L0)
//   X0     : [49152, 81920)    64 x 256 f16 swizzled
//   X2     : [0, 24576)        64 x 192 f16 swizzled      (AEVBUF dead)
//   PANEL2 : [24576, 40960)    32 x 128 f32 weight panel  (PANEL0 dead)
//   X4     : [24576, 45568)    64 x 164 f16 plain         (PANEL2 dead)
//   PANEL4 : [49152, 73728)    32 x 192 f32 weight panel  (X0 dead)
//   PART   : [45568, 47616)    512 f32
#define AEVBUF_OFF 0
#define PANEL0_OFF 24576
#define X0_OFF     49152
#define X2_OFF     0
#define PANEL2_OFF 24576
#define X4_OFF     24576
#define PANEL4_OFF 49152
#define PART_OFF   45568

__global__ __launch_bounds__(512, 4) void nn_kernel(
    const float* __restrict__ aev,
    const float* __restrict__ w0, const float* __restrict__ b0,
    const float* __restrict__ w2, const float* __restrict__ b2,
    const float* __restrict__ w4, const float* __restrict__ b4,
    const float* __restrict__ w6, const float* __restrict__ b6,
    float* __restrict__ out)
{
    __shared__ __align__(16) unsigned char smem_raw[81920];

    const int tid  = threadIdx.x;
    const int wave = tid >> 6;          // 0..7
    const int lane = tid & 63;
    const int col  = lane & 15;
    const int quad = lane >> 4;
    const int tb   = wave >> 2;         // tile within 2-tile panel (0/1)
    const int nt   = wave & 3;          // batch n-tile (0..3), fixed per wave
    const int brow = nt * 16 + col;     // this lane's batch row (0..63)

    // XCD-locality: all 8 model-blocks of atom a land on the same XCD.
    const int a  = blockIdx.x & 127;
    const int m  = blockIdx.x >> 7;
    const int am = a * 8 + m;

    const float* w0p = w0 + (size_t)am * O0_ * D_;
    const float* b0p = b0 + am * O0_;
    const float* w2p = w2 + (size_t)am * O2_ * O0_;
    const float* b2p = b2 + am * O2_;
    const float* w4p = w4 + (size_t)am * O4_ * O2_;
    const float* b4p = b4 + am * O4_;
    const float* w6p = w6 + am * O4_;
    const float  b6v = b6[am];

    _Float16* aevbuf = (_Float16*)(smem_raw + AEVBUF_OFF);   // [64][192]
    _Float16* X0     = (_Float16*)(smem_raw + X0_OFF);       // [64][256]
    _Float16* X2     = (_Float16*)(smem_raw + X2_OFF);       // [64][192]
    _Float16* X4     = (_Float16*)(smem_raw + X4_OFF);       // [64][164]
    float*    part   = (float*)(smem_raw + PART_OFF);

    // ---------------- Layer 0: 384 -> 256 ----------------
    // kc outer (aev K-half staged once per kc), op inner over 8 row-pairs;
    // acc[op] persists across both kc halves. Wave computes (tile=op*2+tb, nt).
    f32x4 acc0[8];
    #pragma unroll
    for (int op = 0; op < 8; ++op) acc0[op] = zero4();

    #pragma unroll
    for (int kc = 0; kc < 2; ++kc) {
        __syncthreads();   // readers of previous aev half done
        // stage aev K-half: 64 rows x 24 chunks of 8 f32 -> f16, swizzled
        #pragma unroll
        for (int it = 0; it < 3; ++it) {
            const int idx = tid + it * 512;
            const int b = idx / 24;
            const int c = idx % 24;
            const float* src = aev + ((size_t)b * A_ + a) * D_ + kc * 192 + c * 8;
            f32x4 lo = *(const f32x4*)src;
            f32x4 hi = *(const f32x4*)(src + 4);
            f16x8 h;
            h[0] = (_Float16)lo[0]; h[1] = (_Float16)lo[1];
            h[2] = (_Float16)lo[2]; h[3] = (_Float16)lo[3];
            h[4] = (_Float16)hi[0]; h[5] = (_Float16)hi[1];
            h[6] = (_Float16)hi[2]; h[7] = (_Float16)hi[3];
            *(f16x8*)(aevbuf + b * 192 + ((c ^ (b & 7)) * 8)) = h;
        }
        #pragma unroll
        for (int op = 0; op < 8; ++op) {
            __syncthreads();   // panel buffer reuse guard (+ aev visibility)
            stage_panel<D_, 192>(w0p, op * 32, kc * 192,
                                 smem_raw + PANEL0_OFF, wave, lane);
            __syncthreads();   // vmcnt(0) drain -> panel visible to all waves
            const int rr = tb * 16 + col;
            #pragma unroll
            for (int ksl = 0; ksl < 6; ++ksl) {
                const f16x8 af = read_afrag<192>(smem_raw + PANEL0_OFF, rr, ksl, quad);
                const int c = (quad + ksl * 4) ^ (brow & 7);
                const f16x8 bf = *(const f16x8*)(aevbuf + brow * 192 + c * 8);
                acc0[op] = __builtin_amdgcn_mfma_f32_16x16x32_f16(af, bf, acc0[op], 0, 0, 0);
            }
        }
    }
    // L0 epilogue -> X0 (pitch 256, swizzled). X0 region untouched so far.
    #pragma unroll
    for (int op = 0; op < 8; ++op) {
        const int tile = op * 2 + tb;
        const int o0 = tile * 16 + quad * 4;
        const f32x4 bias4 = *(const f32x4*)(b0p + o0);
        f16x4 h;
        #pragma unroll
        for (int r = 0; r < 4; ++r) h[r] = (_Float16)celu_f(acc0[op][r] + bias4[r]);
        const int c = o0 >> 3;
        *(f16x4*)(X0 + brow * 256 + ((c ^ (brow & 7)) * 8) + (o0 & 7)) = h;
    }
    __syncthreads();

    // ---------------- Layer 2: 256 -> 192 (6 row-pairs, 2 K-halves) --------
    #pragma unroll
    for (int op = 0; op < 6; ++op) {
        f32x4 acc = zero4();
        #pragma unroll
        for (int kc = 0; kc < 2; ++kc) {
            __syncthreads();   // panel buffer reuse guard
            stage_panel<O0_, 128>(w2p, op * 32, kc * 128,
                                  smem_raw + PANEL2_OFF, wave, lane);
            __syncthreads();   // panel visible
            const int rr = tb * 16 + col;
            #pragma unroll
            for (int ksl = 0; ksl < 4; ++ksl) {
                const f16x8 af = read_afrag<128>(smem_raw + PANEL2_OFF, rr, ksl, quad);
                const int ksg = kc * 4 + ksl;
                const int c = (quad + ksg * 4) ^ (brow & 7);
                const f16x8 bf = *(const f16x8*)(X0 + brow * 256 + c * 8);
                acc = __builtin_amdgcn_mfma_f32_16x16x32_f16(af, bf, acc, 0, 0, 0);
            }
        }
        // epilogue -> X2 (pitch 192, swizzled); per-wave disjoint region
        const int tile = op * 2 + tb;
        const int o0 = tile * 16 + quad * 4;
        const f32x4 bias4 = *(const f32x4*)(b2p + o0);
        f16x4 h;
        #pragma unroll
        for (int r = 0; r < 4; ++r) h[r] = (_Float16)celu_f(acc[r] + bias4[r]);
        const int c = o0 >> 3;
        *(f16x4*)(X2 + brow * 192 + ((c ^ (brow & 7)) * 8) + (o0 & 7)) = h;
    }
    __syncthreads();

    // ---------------- Layer 4: 192 -> 160 (5 row-pairs, full-K panels) -----
    // Panels are fully contiguous 24-KB global streams (row stride == K).
    #pragma unroll
    for (int op = 0; op < 5; ++op) {
        f32x4 acc = zero4();
        __syncthreads();   // panel buffer reuse guard
        stage_panel<O2_, 192>(w4p, op * 32, 0,
                              smem_raw + PANEL4_OFF, wave, lane);
        __syncthreads();   // panel visible
        const int rr = tb * 16 + col;
        #pragma unroll
        for (int ksl = 0; ksl < 6; ++ksl) {
            const f16x8 af = read_afrag<192>(smem_raw + PANEL4_OFF, rr, ksl, quad);
            const int c = (quad + ksl * 4) ^ (brow & 7);
            const f16x8 bf = *(const f16x8*)(X2 + brow * 192 + c * 8);
            acc = __builtin_amdgcn_mfma_f32_16x16x32_f16(af, bf, acc, 0, 0, 0);
        }
        // epilogue -> X4 (plain, pitch 164)
        const int tile = op * 2 + tb;
        const int o0 = tile * 16 + quad * 4;
        const f32x4 bias4 = *(const f32x4*)(b4p + o0);
        f16x4 h;
        #pragma unroll
        for (int r = 0; r < 4; ++r) h[r] = (_Float16)celu_f(acc[r] + bias4[r]);
        *(f16x4*)(X4 + brow * 164 + o0) = h;
    }
    __syncthreads();

    // ---------------- Layer 6: 160 -> 1, VALU dot ----------------
    {
        const int b  = tid & 63;
        const int pt = tid >> 6;              // 0..7, 20 elems each
        const _Float16* xrow = X4 + b * 164 + pt * 20;
        const float* wseg = w6p + pt * 20;
        float s = 0.f;
        #pragma unroll
        for (int j = 0; j < 5; ++j) {
            f32x4 wv = *(const f32x4*)(wseg + j * 4);
            f16x4 xv = *(const f16x4*)(xrow + j * 4);
            s += wv[0] * (float)xv[0] + wv[1] * (float)xv[1] +
                 wv[2] * (float)xv[2] + wv[3] * (float)xv[3];
        }
        part[tid] = s;
    }
    __syncthreads();
    if (tid < 64) {
        float x6 = b6v;
        #pragma unroll
        for (int p = 0; p < 8; ++p) x6 += part[tid + 64 * p];
        atomicAdd(out + B_ * A_ + tid, x6 * 0.125f);  // /M
    }
}

__global__ void init_out_kernel(const int* __restrict__ species, float* __restrict__ out) {
    const int i = blockIdx.x * 256 + threadIdx.x;
    if (i < B_ * A_) out[i] = (float)species[i];
    if (i < B_) out[B_ * A_ + i] = 0.f;
}

extern "C" void kernel_launch(void* const* d_in, const int* in_sizes, int n_in,
                              void* d_out, int out_size, void* d_ws, size_t ws_size,
                              hipStream_t stream) {
    const int*   species = (const int*)d_in[0];
    const float* aev = (const float*)d_in[1];
    const float* w0  = (const float*)d_in[2];
    const float* b0  = (const float*)d_in[3];
    const float* w2  = (const float*)d_in[4];
    const float* b2  = (const float*)d_in[5];
    const float* w4  = (const float*)d_in[6];
    const float* b4  = (const float*)d_in[7];
    const float* w6  = (const float*)d_in[8];
    const float* b6  = (const float*)d_in[9];
    float* out = (float*)d_out;

    hipLaunchKernelGGL(init_out_kernel, dim3(32), dim3(256), 0, stream, species, out);
    hipLaunchKernelGGL(nn_kernel, dim3(A_ * M_), dim3(512), 0, stream,
                       aev, w0, b0, w2, b2, w4, b4, w6, b6, out);
}